// Round 6
// baseline (531.062 us; speedup 1.0000x reference)
//
#include <hip/hip_runtime.h>
#include <math.h>

#define N_NODES 50000
#define N_EDGES 800000
#define DIM 64
#define N_LAYERS 5

#define BLK 256
#define ROWS 64      // nodes per block (16 per wave)
#define HSTRIDE 65   // bank = (row + k) % 32 -> at most 2-way across a wave (free)

#define SCAN_BLOCKS ((N_NODES + 255) / 256)   // 196

// ---------------- CSR build (per call; ws is re-poisoned every launch) ----------------

__global__ __launch_bounds__(256) void hist_kernel(const int* __restrict__ dst,
                                                   int* __restrict__ counts) {
    int e = blockIdx.x * 256 + threadIdx.x;
    if (e < N_EDGES) atomicAdd(&counts[dst[e]], 1);
}

__global__ __launch_bounds__(256) void scan_a(const int* __restrict__ counts,
                                              int* __restrict__ rowptr,
                                              int* __restrict__ blockSums) {
    __shared__ int s[256];
    int t = threadIdx.x;
    int g = blockIdx.x * 256 + t;
    int v = (g < N_NODES) ? counts[g] : 0;
    s[t] = v;
    __syncthreads();
    #pragma unroll
    for (int off = 1; off < 256; off <<= 1) {
        int u = (t >= off) ? s[t - off] : 0;
        __syncthreads();
        s[t] += u;
        __syncthreads();
    }
    if (g < N_NODES) rowptr[g] = s[t] - v;
    if (t == 255) blockSums[blockIdx.x] = s[255];
}

__global__ __launch_bounds__(256) void scan_b(const int* __restrict__ blockSums,
                                              int* __restrict__ blockOffs) {
    __shared__ int s[256];
    int t = threadIdx.x;
    int v = (t < SCAN_BLOCKS) ? blockSums[t] : 0;
    s[t] = v;
    __syncthreads();
    #pragma unroll
    for (int off = 1; off < 256; off <<= 1) {
        int u = (t >= off) ? s[t - off] : 0;
        __syncthreads();
        s[t] += u;
        __syncthreads();
    }
    if (t < SCAN_BLOCKS) blockOffs[t] = s[t] - v;
}

__global__ __launch_bounds__(256) void scan_c(int* __restrict__ rowptr,
                                              const int* __restrict__ blockOffs) {
    int t = threadIdx.x;
    int g = blockIdx.x * 256 + t;
    if (g < N_NODES) rowptr[g] += blockOffs[blockIdx.x];
    if (g == 0) rowptr[N_NODES] = N_EDGES;
}

__global__ __launch_bounds__(256) void fill_kernel(const int* __restrict__ src,
                                                   const int* __restrict__ dst,
                                                   const int* __restrict__ rowptr,
                                                   int* __restrict__ cursor,
                                                   int* __restrict__ csr_src) {
    int e = blockIdx.x * 256 + threadIdx.x;
    if (e >= N_EDGES) return;
    int d = dst[e];
    int pos = atomicAdd(&cursor[d], 1);
    csr_src[rowptr[d] + pos] = src[e];
}

// ---------------- fused layer: gather (-> LDS) + 3x Dense+ReLU + pool partial ----------------
// Gather: one wave per node, lane = column. All <=64 edge indices loaded in ONE
// coalesced vector load, broadcast via v_readlane (uniform base -> saddr loads).
// 4-wide unroll = 4 independent 256B row loads in flight per wave.
// MLP: wave q owns 16-col slice, lane = row; W rows are wave-uniform s_loads.
__global__ __launch_bounds__(BLK) void layer_kernel(const float* __restrict__ h,
                                                    const int* __restrict__ rowptr,
                                                    const int* __restrict__ csr_src,
                                                    const float* __restrict__ W,   // [3][64][64]
                                                    float* __restrict__ h_out,
                                                    float* __restrict__ pooled) {  // [64]
    __shared__ float H[ROWS * HSTRIDE];   // 16.6 KB
    const int tid  = threadIdx.x;
    const int lane = tid & 63;
    const int w    = __builtin_amdgcn_readfirstlane(tid >> 6);   // wave id 0..3
    const int row0 = blockIdx.x * ROWS;

    // ---- gather phase: wave w fills rows [w*16, w*16+16) ----
    for (int j = 0; j < 16; ++j) {
        const int r = w * 16 + j;
        const int n = __builtin_amdgcn_readfirstlane(row0 + r);
        float acc = 0.f;
        if (n < N_NODES) {
            float self = h[(size_t)n * DIM + lane];
            acc = self;
            const int e0 = rowptr[n], e1 = rowptr[n + 1];
            for (int base = e0; base < e1; base += 64) {
                const int m  = min(64, e1 - base);          // wave-uniform
                const int mr = (m + 3) & ~3;
                // lanes >= m pad with self; pre-subtract the padded adds
                int idx = (lane < m) ? csr_src[base + lane] : n;
                acc -= (float)(mr - m) * self;
                for (int jj = 0; jj < mr; jj += 4) {
                    int s0 = __builtin_amdgcn_readlane(idx, jj + 0);
                    int s1 = __builtin_amdgcn_readlane(idx, jj + 1);
                    int s2 = __builtin_amdgcn_readlane(idx, jj + 2);
                    int s3 = __builtin_amdgcn_readlane(idx, jj + 3);
                    float v0 = h[(size_t)s0 * DIM + lane];
                    float v1 = h[(size_t)s1 * DIM + lane];
                    float v2 = h[(size_t)s2 * DIM + lane];
                    float v3 = h[(size_t)s3 * DIM + lane];
                    acc += (v0 + v1) + (v2 + v3);
                }
            }
        }
        H[r * HSTRIDE + lane] = acc;   // conflict-free (lane varies)
    }
    __syncthreads();

    // ---- MLP phase ----
    const int row = lane;
    const int q   = w;                       // 16-col slice id (wave-uniform)
    const float* hrow = &H[row * HSTRIDE];

    for (int p = 0; p < 3; ++p) {
        const float* Wq = W + p * DIM * DIM + q * 16;
        float4 acc0 = make_float4(0.f, 0.f, 0.f, 0.f);
        float4 acc1 = make_float4(0.f, 0.f, 0.f, 0.f);
        float4 acc2 = make_float4(0.f, 0.f, 0.f, 0.f);
        float4 acc3 = make_float4(0.f, 0.f, 0.f, 0.f);
        #pragma unroll 8
        for (int k = 0; k < DIM; ++k) {
            float hk = hrow[k];                 // ds_read_b32, <=2-way bank alias (free)
            const float* wr = Wq + k * DIM;     // wave-uniform -> s_load_dwordx16
            float4 w0 = *(const float4*)(wr + 0);
            float4 w1 = *(const float4*)(wr + 4);
            float4 w2 = *(const float4*)(wr + 8);
            float4 w3 = *(const float4*)(wr + 12);
            acc0.x = fmaf(hk, w0.x, acc0.x); acc0.y = fmaf(hk, w0.y, acc0.y);
            acc0.z = fmaf(hk, w0.z, acc0.z); acc0.w = fmaf(hk, w0.w, acc0.w);
            acc1.x = fmaf(hk, w1.x, acc1.x); acc1.y = fmaf(hk, w1.y, acc1.y);
            acc1.z = fmaf(hk, w1.z, acc1.z); acc1.w = fmaf(hk, w1.w, acc1.w);
            acc2.x = fmaf(hk, w2.x, acc2.x); acc2.y = fmaf(hk, w2.y, acc2.y);
            acc2.z = fmaf(hk, w2.z, acc2.z); acc2.w = fmaf(hk, w2.w, acc2.w);
            acc3.x = fmaf(hk, w3.x, acc3.x); acc3.y = fmaf(hk, w3.y, acc3.y);
            acc3.z = fmaf(hk, w3.z, acc3.z); acc3.w = fmaf(hk, w3.w, acc3.w);
        }
        __syncthreads();   // all reads of H done before overwrite
        float* hw = &H[row * HSTRIDE + q * 16];
        acc0.x = fmaxf(acc0.x, 0.f); acc0.y = fmaxf(acc0.y, 0.f);
        acc0.z = fmaxf(acc0.z, 0.f); acc0.w = fmaxf(acc0.w, 0.f);
        acc1.x = fmaxf(acc1.x, 0.f); acc1.y = fmaxf(acc1.y, 0.f);
        acc1.z = fmaxf(acc1.z, 0.f); acc1.w = fmaxf(acc1.w, 0.f);
        acc2.x = fmaxf(acc2.x, 0.f); acc2.y = fmaxf(acc2.y, 0.f);
        acc2.z = fmaxf(acc2.z, 0.f); acc2.w = fmaxf(acc2.w, 0.f);
        acc3.x = fmaxf(acc3.x, 0.f); acc3.y = fmaxf(acc3.y, 0.f);
        acc3.z = fmaxf(acc3.z, 0.f); acc3.w = fmaxf(acc3.w, 0.f);
        *(float4*)(hw + 0)  = acc0;
        *(float4*)(hw + 4)  = acc1;
        *(float4*)(hw + 8)  = acc2;
        *(float4*)(hw + 12) = acc3;
        __syncthreads();
    }

    // ---- store h for next layer (coalesced) ----
    #pragma unroll
    for (int i = 0; i < 4; ++i) {
        int f4 = tid + i * BLK;
        int r  = f4 >> 4;
        int c  = (f4 & 15) << 2;
        int grow = row0 + r;
        if (grow < N_NODES)
            *(float4*)(h_out + (size_t)grow * DIM + c) = *(const float4*)&H[r * HSTRIDE + c];
    }

    // ---- global mean pool partial (OOB rows hold zeros... only if gather wrote 0;
    //      they do: acc stays 0 for n >= N_NODES, and MLP of 0 is 0 (relu(0)=0)) ----
    if (tid < 64) {
        float s = 0.f;
        #pragma unroll 8
        for (int r = 0; r < ROWS; ++r)
            s += H[r * HSTRIDE + tid];
        atomicAdd(&pooled[tid], s);
    }
}

__global__ void finalize_kernel(const float* __restrict__ pooled,
                                const float* __restrict__ Wl,
                                float* __restrict__ out) {
    int c = threadIdx.x;  // 64
    float s = 0.f;
    #pragma unroll
    for (int l = 0; l < N_LAYERS; ++l)
        s += pooled[l * DIM + c] * Wl[l * DIM + c];
    #pragma unroll
    for (int off = 32; off > 0; off >>= 1)
        s += __shfl_down(s, off, 64);
    if (c == 0) {
        float logit = s / (float)N_NODES;
        out[0] = 1.f / (1.f + expf(-logit));
    }
}

extern "C" void kernel_launch(void* const* d_in, const int* in_sizes, int n_in,
                              void* d_out, int out_size, void* d_ws, size_t ws_size,
                              hipStream_t stream) {
    const float* x   = (const float*)d_in[0];
    const float* W   = (const float*)d_in[1];
    const float* Wl  = (const float*)d_in[2];
    const int*   src = (const int*)d_in[3];
    const int*   dst = (const int*)d_in[4];
    float* out = (float*)d_out;

    char* ws = (char*)d_ws;
    const size_t nodeBytes = (size_t)N_NODES * DIM * sizeof(float);   // 12.8 MB
    float* hA       = (float*)(ws);
    float* hB       = (float*)(ws + nodeBytes);
    int*   csr_src  = (int*)  (ws + 2 * nodeBytes);                   // 3.2 MB
    int*   rowptr   = (int*)  (ws + 2 * nodeBytes + (size_t)N_EDGES * 4);
    int*   counts   = rowptr + (N_NODES + 1);
    int*   cursor   = counts + N_NODES;
    int*   blockSums= cursor + N_NODES;
    int*   blockOffs= blockSums + SCAN_BLOCKS;
    float* pooled   = (float*)(blockOffs + SCAN_BLOCKS);              // 5*64 floats

    hipMemsetAsync(counts, 0, N_NODES * sizeof(int), stream);
    hipMemsetAsync(cursor, 0, N_NODES * sizeof(int), stream);
    hipMemsetAsync(pooled, 0, N_LAYERS * DIM * sizeof(float), stream);

    hist_kernel<<<(N_EDGES + 255) / 256, 256, 0, stream>>>(dst, counts);
    scan_a<<<SCAN_BLOCKS, 256, 0, stream>>>(counts, rowptr, blockSums);
    scan_b<<<1, 256, 0, stream>>>(blockSums, blockOffs);
    scan_c<<<SCAN_BLOCKS, 256, 0, stream>>>(rowptr, blockOffs);
    fill_kernel<<<(N_EDGES + 255) / 256, 256, 0, stream>>>(src, dst, rowptr, cursor, csr_src);

    const float* hcur = x;
    float* hnext = hA;
    for (int l = 0; l < N_LAYERS; ++l) {
        layer_kernel<<<(N_NODES + ROWS - 1) / ROWS, BLK, 0, stream>>>(
            hcur, rowptr, csr_src, W + (size_t)l * 3 * DIM * DIM, hnext, pooled + l * DIM);
        hcur = hnext;
        hnext = (hnext == hA) ? hB : hA;
    }
    finalize_kernel<<<1, 64, 0, stream>>>(pooled, Wl, out);
}

// Round 7
// 477.820 us; speedup vs baseline: 1.1114x; 1.1114x over previous
//
#include <hip/hip_runtime.h>
#include <math.h>

#define N_NODES 50000
#define N_EDGES 800000
#define DIM 64
#define N_LAYERS 5

#define BLK 256
#define ROWS 64      // nodes per block (16 per wave)
#define HSTRIDE 68   // 272B row stride: 16B-aligned for ds_read_b128; bank=(4r+lane)%32 conflict-free

#define SCAN_BLOCKS ((N_NODES + 255) / 256)   // 196
#define WFRAG_PER_LAYER (3 * 2 * 4 * 2 * 64 * 8)   // 24576 shorts = 49152 B

typedef __attribute__((ext_vector_type(8))) short short8;
typedef __attribute__((ext_vector_type(4))) float floatx4;

__device__ inline unsigned short bf16_rne(float f) {
    unsigned int u = __float_as_uint(f);
    return (unsigned short)((u + 0x7FFFu + ((u >> 16) & 1u)) >> 16);
}
__device__ inline float bf16_f(unsigned short h) {
    return __uint_as_float(((unsigned int)h) << 16);
}

// ---------------- CSR build ----------------

__global__ __launch_bounds__(256) void hist_kernel(const int* __restrict__ dst,
                                                   int* __restrict__ counts) {
    int e = blockIdx.x * 256 + threadIdx.x;
    if (e < N_EDGES) atomicAdd(&counts[dst[e]], 1);
}

__global__ __launch_bounds__(256) void scan_a(const int* __restrict__ counts,
                                              int* __restrict__ rowptr,
                                              int* __restrict__ blockSums) {
    __shared__ int s[256];
    int t = threadIdx.x;
    int g = blockIdx.x * 256 + t;
    int v = (g < N_NODES) ? counts[g] : 0;
    s[t] = v;
    __syncthreads();
    #pragma unroll
    for (int off = 1; off < 256; off <<= 1) {
        int u = (t >= off) ? s[t - off] : 0;
        __syncthreads();
        s[t] += u;
        __syncthreads();
    }
    if (g < N_NODES) rowptr[g] = s[t] - v;
    if (t == 255) blockSums[blockIdx.x] = s[255];
}

__global__ __launch_bounds__(256) void scan_b(const int* __restrict__ blockSums,
                                              int* __restrict__ blockOffs) {
    __shared__ int s[256];
    int t = threadIdx.x;
    int v = (t < SCAN_BLOCKS) ? blockSums[t] : 0;
    s[t] = v;
    __syncthreads();
    #pragma unroll
    for (int off = 1; off < 256; off <<= 1) {
        int u = (t >= off) ? s[t - off] : 0;
        __syncthreads();
        s[t] += u;
        __syncthreads();
    }
    if (t < SCAN_BLOCKS) blockOffs[t] = s[t] - v;
}

__global__ __launch_bounds__(256) void scan_c(int* __restrict__ rowptr,
                                              const int* __restrict__ blockOffs) {
    int t = threadIdx.x;
    int g = blockIdx.x * 256 + t;
    if (g < N_NODES) rowptr[g] += blockOffs[blockIdx.x];
    if (g == 0) rowptr[N_NODES] = N_EDGES;
}

__global__ __launch_bounds__(256) void fill_kernel(const int* __restrict__ src,
                                                   const int* __restrict__ dst,
                                                   const int* __restrict__ rowptr,
                                                   int* __restrict__ cursor,
                                                   int* __restrict__ csr_src) {
    int e = blockIdx.x * 256 + threadIdx.x;
    if (e >= N_EDGES) return;
    int d = dst[e];
    int pos = atomicAdd(&cursor[d], 1);
    csr_src[rowptr[d] + pos] = src[e];
}

// ---------------- W -> split-bf16 MFMA B-fragments ----------------
// Fragment order: [layer][p][kt][nt][hl][lane][j]; element = W[k = kt*32+(lane>>4)*8+j]
// [n = nt*16+(lane&15)]. hl=0: bf16_rne(v); hl=1: bf16_rne(v - hi).
__global__ __launch_bounds__(256) void wprep_kernel(const float* __restrict__ W,
                                                    unsigned short* __restrict__ wfrag) {
    int t = blockIdx.x * 256 + threadIdx.x;
    if (t >= N_LAYERS * WFRAG_PER_LAYER) return;
    int j    = t & 7;
    int lane = (t >> 3) & 63;
    int hl   = (t >> 9) & 1;
    int nt   = (t >> 10) & 3;
    int kt   = (t >> 12) & 1;
    int rest = t >> 13;
    int p    = rest % 3;
    int layer= rest / 3;
    int k = kt * 32 + (lane >> 4) * 8 + j;
    int n = nt * 16 + (lane & 15);
    float v = W[(((size_t)layer * 3 + p) * 64 + k) * 64 + n];
    unsigned short hi = bf16_rne(v);
    unsigned short out = hl ? bf16_rne(v - bf16_f(hi)) : hi;
    wfrag[t] = out;
}

// ---------------- fused layer: gather (-> LDS) + 3x MFMA Dense+ReLU + pool partial ----------------
__global__ __launch_bounds__(BLK) void layer_kernel(const float* __restrict__ h,
                                                    const int* __restrict__ rowptr,
                                                    const int* __restrict__ csr_src,
                                                    const unsigned short* __restrict__ wf, // this layer's frags
                                                    float* __restrict__ h_out,
                                                    float* __restrict__ pooled) {  // [64]
    __shared__ float H[ROWS * HSTRIDE];   // 17.4 KB
    const int tid  = threadIdx.x;
    const int lane = tid & 63;
    const int w    = __builtin_amdgcn_readfirstlane(tid >> 6);   // wave id 0..3
    const int row0 = blockIdx.x * ROWS;

    // ---- gather phase: wave w fills rows [w*16, w*16+16) (unchanged from R5) ----
    for (int j = 0; j < 16; ++j) {
        const int r = w * 16 + j;
        const int n = __builtin_amdgcn_readfirstlane(row0 + r);
        float acc = 0.f;
        if (n < N_NODES) {
            float self = h[(size_t)n * DIM + lane];
            acc = self;
            const int e0 = rowptr[n], e1 = rowptr[n + 1];
            for (int base = e0; base < e1; base += 64) {
                const int m  = min(64, e1 - base);          // wave-uniform
                const int mr = (m + 3) & ~3;
                int idx = (lane < m) ? csr_src[base + lane] : n;
                acc -= (float)(mr - m) * self;
                for (int jj = 0; jj < mr; jj += 4) {
                    int s0 = __builtin_amdgcn_readlane(idx, jj + 0);
                    int s1 = __builtin_amdgcn_readlane(idx, jj + 1);
                    int s2 = __builtin_amdgcn_readlane(idx, jj + 2);
                    int s3 = __builtin_amdgcn_readlane(idx, jj + 3);
                    float v0 = h[(size_t)s0 * DIM + lane];
                    float v1 = h[(size_t)s1 * DIM + lane];
                    float v2 = h[(size_t)s2 * DIM + lane];
                    float v3 = h[(size_t)s3 * DIM + lane];
                    acc += (v0 + v1) + (v2 + v3);
                }
            }
        }
        H[r * HSTRIDE + lane] = acc;
    }
    __syncthreads();

    // ---- MLP phase: split-bf16 MFMA. Wave w owns rows m0..m0+16, all 64 cols ----
    const int m0 = w * 16;
    const int mrow = lane & 15;       // A fragment m index
    const int quad = lane >> 4;       // A fragment k-group
    const short8* Bf = (const short8*)wf;

    for (int p = 0; p < 3; ++p) {
        // A fragments from LDS (hi/lo split)
        short8 Ahi[2], Alo[2];
        #pragma unroll
        for (int kt = 0; kt < 2; ++kt) {
            const float* ap = &H[(m0 + mrow) * HSTRIDE + kt * 32 + quad * 8];
            float4 f0 = *(const float4*)ap;
            float4 f1 = *(const float4*)(ap + 4);
            float fv[8] = {f0.x, f0.y, f0.z, f0.w, f1.x, f1.y, f1.z, f1.w};
            short8 hi, lo;
            #pragma unroll
            for (int jj = 0; jj < 8; ++jj) {
                unsigned short hb = bf16_rne(fv[jj]);
                hi[jj] = (short)hb;
                lo[jj] = (short)bf16_rne(fv[jj] - bf16_f(hb));
            }
            Ahi[kt] = hi; Alo[kt] = lo;
        }

        floatx4 acc[4];
        #pragma unroll
        for (int nt = 0; nt < 4; ++nt) { acc[nt][0]=0.f; acc[nt][1]=0.f; acc[nt][2]=0.f; acc[nt][3]=0.f; }

        #pragma unroll
        for (int nt = 0; nt < 4; ++nt) {
            #pragma unroll
            for (int kt = 0; kt < 2; ++kt) {
                int fbase = (((p * 2 + kt) * 4 + nt) * 2) * 64 + lane;
                short8 bhi = Bf[fbase];
                short8 blo = Bf[fbase + 64];
                acc[nt] = __builtin_amdgcn_mfma_f32_16x16x32_bf16(Alo[kt], bhi, acc[nt], 0, 0, 0);
                acc[nt] = __builtin_amdgcn_mfma_f32_16x16x32_bf16(Ahi[kt], blo, acc[nt], 0, 0, 0);
                acc[nt] = __builtin_amdgcn_mfma_f32_16x16x32_bf16(Ahi[kt], bhi, acc[nt], 0, 0, 0);
            }
        }
        __syncthreads();   // all waves done reading H (A frags) before overwrite

        // write back relu(D): C/D layout col=lane&15, row=quad*4+reg
        #pragma unroll
        for (int nt = 0; nt < 4; ++nt) {
            #pragma unroll
            for (int reg = 0; reg < 4; ++reg) {
                int row = m0 + quad * 4 + reg;
                H[row * HSTRIDE + nt * 16 + mrow] = fmaxf(acc[nt][reg], 0.f);
            }
        }
        __syncthreads();
    }

    // ---- store h for next layer (coalesced) ----
    #pragma unroll
    for (int i = 0; i < 4; ++i) {
        int f4 = tid + i * BLK;
        int r  = f4 >> 4;
        int c  = (f4 & 15) << 2;
        int grow = row0 + r;
        if (grow < N_NODES)
            *(float4*)(h_out + (size_t)grow * DIM + c) = *(const float4*)&H[r * HSTRIDE + c];
    }

    // ---- global mean pool partial (OOB rows are zero: gather wrote 0, relu(0*W)=0) ----
    if (tid < 64) {
        float s = 0.f;
        #pragma unroll 8
        for (int r = 0; r < ROWS; ++r)
            s += H[r * HSTRIDE + tid];
        atomicAdd(&pooled[tid], s);
    }
}

__global__ void finalize_kernel(const float* __restrict__ pooled,
                                const float* __restrict__ Wl,
                                float* __restrict__ out) {
    int c = threadIdx.x;  // 64
    float s = 0.f;
    #pragma unroll
    for (int l = 0; l < N_LAYERS; ++l)
        s += pooled[l * DIM + c] * Wl[l * DIM + c];
    #pragma unroll
    for (int off = 32; off > 0; off >>= 1)
        s += __shfl_down(s, off, 64);
    if (c == 0) {
        float logit = s / (float)N_NODES;
        out[0] = 1.f / (1.f + expf(-logit));
    }
}

extern "C" void kernel_launch(void* const* d_in, const int* in_sizes, int n_in,
                              void* d_out, int out_size, void* d_ws, size_t ws_size,
                              hipStream_t stream) {
    const float* x   = (const float*)d_in[0];
    const float* W   = (const float*)d_in[1];
    const float* Wl  = (const float*)d_in[2];
    const int*   src = (const int*)d_in[3];
    const int*   dst = (const int*)d_in[4];
    float* out = (float*)d_out;

    char* ws = (char*)d_ws;
    const size_t nodeBytes = (size_t)N_NODES * DIM * sizeof(float);   // 12.8 MB
    float* hA       = (float*)(ws);
    float* hB       = (float*)(ws + nodeBytes);
    int*   csr_src  = (int*)  (ws + 2 * nodeBytes);                   // 3.2 MB
    int*   rowptr   = (int*)  (ws + 2 * nodeBytes + (size_t)N_EDGES * 4);
    int*   counts   = rowptr + (N_NODES + 1);
    int*   cursor   = counts + N_NODES;
    int*   blockSums= cursor + N_NODES;
    int*   blockOffs= blockSums + SCAN_BLOCKS;
    float* pooled   = (float*)(blockOffs + SCAN_BLOCKS);              // 5*64 floats
    unsigned short* wfrag = (unsigned short*)(pooled + N_LAYERS * DIM); // 240 KB

    hipMemsetAsync(counts, 0, N_NODES * sizeof(int), stream);
    hipMemsetAsync(cursor, 0, N_NODES * sizeof(int), stream);
    hipMemsetAsync(pooled, 0, N_LAYERS * DIM * sizeof(float), stream);

    wprep_kernel<<<(N_LAYERS * WFRAG_PER_LAYER + 255) / 256, 256, 0, stream>>>(W, wfrag);
    hist_kernel<<<(N_EDGES + 255) / 256, 256, 0, stream>>>(dst, counts);
    scan_a<<<SCAN_BLOCKS, 256, 0, stream>>>(counts, rowptr, blockSums);
    scan_b<<<1, 256, 0, stream>>>(blockSums, blockOffs);
    scan_c<<<SCAN_BLOCKS, 256, 0, stream>>>(rowptr, blockOffs);
    fill_kernel<<<(N_EDGES + 255) / 256, 256, 0, stream>>>(src, dst, rowptr, cursor, csr_src);

    const float* hcur = x;
    float* hnext = hA;
    for (int l = 0; l < N_LAYERS; ++l) {
        layer_kernel<<<(N_NODES + ROWS - 1) / ROWS, BLK, 0, stream>>>(
            hcur, rowptr, csr_src, wfrag + (size_t)l * WFRAG_PER_LAYER, hnext, pooled + l * DIM);
        hcur = hnext;
        hnext = (hnext == hA) ? hB : hA;
    }
    finalize_kernel<<<1, 64, 0, stream>>>(pooled, Wl, out);
}

// Round 8
// 345.521 us; speedup vs baseline: 1.5370x; 1.3829x over previous
//
#include <hip/hip_runtime.h>
#include <math.h>

#define N_NODES 50000
#define N_EDGES 800000
#define DIM 64
#define N_LAYERS 5

#define BLK 64       // one wave per block
#define ROWS 16      // 50000 = 3125 * 16 exactly -> no bounds checks
#define HSTRIDE 68   // 16B-aligned rows for ds_read_b128; bank=(4r+lane)%32 conflict-free
#define POOL_REP 16  // replicate pooled accumulators to cut same-address atomic serialization

#define SCAN_BLOCKS ((N_NODES + 255) / 256)   // 196
#define WFRAG_PER_LAYER (3 * 2 * 4 * 2 * 64 * 8)   // 24576 shorts = 49152 B

typedef __attribute__((ext_vector_type(8))) short short8;
typedef __attribute__((ext_vector_type(4))) float floatx4;

__device__ inline unsigned short bf16_rne(float f) {
    unsigned int u = __float_as_uint(f);
    return (unsigned short)((u + 0x7FFFu + ((u >> 16) & 1u)) >> 16);
}
__device__ inline float bf16_f(unsigned short h) {
    return __uint_as_float(((unsigned int)h) << 16);
}

// ---------------- CSR build ----------------

__global__ __launch_bounds__(256) void hist_kernel(const int* __restrict__ dst,
                                                   int* __restrict__ counts) {
    int e = blockIdx.x * 256 + threadIdx.x;
    if (e < N_EDGES) atomicAdd(&counts[dst[e]], 1);
}

__global__ __launch_bounds__(256) void scan_a(const int* __restrict__ counts,
                                              int* __restrict__ rowptr,
                                              int* __restrict__ blockSums) {
    __shared__ int s[256];
    int t = threadIdx.x;
    int g = blockIdx.x * 256 + t;
    int v = (g < N_NODES) ? counts[g] : 0;
    s[t] = v;
    __syncthreads();
    #pragma unroll
    for (int off = 1; off < 256; off <<= 1) {
        int u = (t >= off) ? s[t - off] : 0;
        __syncthreads();
        s[t] += u;
        __syncthreads();
    }
    if (g < N_NODES) rowptr[g] = s[t] - v;
    if (t == 255) blockSums[blockIdx.x] = s[255];
}

__global__ __launch_bounds__(256) void scan_b(const int* __restrict__ blockSums,
                                              int* __restrict__ blockOffs) {
    __shared__ int s[256];
    int t = threadIdx.x;
    int v = (t < SCAN_BLOCKS) ? blockSums[t] : 0;
    s[t] = v;
    __syncthreads();
    #pragma unroll
    for (int off = 1; off < 256; off <<= 1) {
        int u = (t >= off) ? s[t - off] : 0;
        __syncthreads();
        s[t] += u;
        __syncthreads();
    }
    if (t < SCAN_BLOCKS) blockOffs[t] = s[t] - v;
}

__global__ __launch_bounds__(256) void scan_c(int* __restrict__ rowptr,
                                              const int* __restrict__ blockOffs) {
    int t = threadIdx.x;
    int g = blockIdx.x * 256 + t;
    if (g < N_NODES) rowptr[g] += blockOffs[blockIdx.x];
    if (g == 0) rowptr[N_NODES] = N_EDGES;
}

__global__ __launch_bounds__(256) void fill_kernel(const int* __restrict__ src,
                                                   const int* __restrict__ dst,
                                                   const int* __restrict__ rowptr,
                                                   int* __restrict__ cursor,
                                                   int* __restrict__ csr_src) {
    int e = blockIdx.x * 256 + threadIdx.x;
    if (e >= N_EDGES) return;
    int d = dst[e];
    int pos = atomicAdd(&cursor[d], 1);
    csr_src[rowptr[d] + pos] = src[e];
}

// ---------------- W -> split-bf16 MFMA B-fragments (unchanged from R6) ----------------
__global__ __launch_bounds__(256) void wprep_kernel(const float* __restrict__ W,
                                                    unsigned short* __restrict__ wfrag) {
    int t = blockIdx.x * 256 + threadIdx.x;
    if (t >= N_LAYERS * WFRAG_PER_LAYER) return;
    int j    = t & 7;
    int lane = (t >> 3) & 63;
    int hl   = (t >> 9) & 1;
    int nt   = (t >> 10) & 3;
    int kt   = (t >> 12) & 1;
    int rest = t >> 13;
    int p    = rest % 3;
    int layer= rest / 3;
    int k = kt * 32 + (lane >> 4) * 8 + j;
    int n = nt * 16 + (lane & 15);
    float v = W[(((size_t)layer * 3 + p) * 64 + k) * 64 + n];
    unsigned short hi = bf16_rne(v);
    unsigned short out = hl ? bf16_rne(v - bf16_f(hi)) : hl ? 0 : hi;
    if (hl) out = bf16_rne(v - bf16_f(hi)); else out = hi;
    wfrag[t] = out;
}

// ---------------- fused layer: one wave per 16 nodes ----------------
// Gather: metadata hoisted (1 coalesced rowptr load, 16 idx loads + 16 self loads
// issued independently up front), then per-row edge loop with 8 row-loads in flight.
// MLP: split-bf16 MFMA on the wave's 16 rows.
__global__ __launch_bounds__(BLK) void layer_kernel(const float* __restrict__ h,
                                                    const int* __restrict__ rowptr,
                                                    const int* __restrict__ csr_src,
                                                    const unsigned short* __restrict__ wf,
                                                    float* __restrict__ h_out,
                                                    float* __restrict__ pooled) {  // [POOL_REP][64]
    __shared__ float H[ROWS * HSTRIDE];   // 4.4 KB
    const int lane = threadIdx.x;
    const int n0   = blockIdx.x * ROWS;

    // rowptr[n0 .. n0+16] in one coalesced load
    int rpv = rowptr[n0 + min(lane, 16)];
    int rp_next = __shfl_down(rpv, 1, 64);
    int degl = rp_next - rpv;
    bool big = __ballot(lane < 16 && degl > 64) != 0ull;   // wave-uniform

    if (!big) {
        // ---- fast path: all degrees <= 64 ----
        int   e0s[16], degs[16];
        #pragma unroll
        for (int j = 0; j < 16; ++j) {
            e0s[j]  = __builtin_amdgcn_readlane(rpv, j);
            degs[j] = __builtin_amdgcn_readlane(rpv, j + 1) - e0s[j];
        }
        int idxv[16];
        #pragma unroll
        for (int j = 0; j < 16; ++j)
            idxv[j] = (lane < degs[j]) ? csr_src[e0s[j] + lane] : (n0 + j);
        float accv[16];
        #pragma unroll
        for (int j = 0; j < 16; ++j)
            accv[j] = h[(size_t)(n0 + j) * DIM + lane];

        #pragma unroll
        for (int j = 0; j < 16; ++j) {
            const int deg = degs[j];
            const int mr  = (deg + 3) & ~3;
            accv[j] *= (float)(1 - (mr - deg));   // pre-cancel padded self-adds
            int jj = 0;
            for (; jj + 8 <= mr; jj += 8) {
                int s0 = __builtin_amdgcn_readlane(idxv[j], jj + 0);
                int s1 = __builtin_amdgcn_readlane(idxv[j], jj + 1);
                int s2 = __builtin_amdgcn_readlane(idxv[j], jj + 2);
                int s3 = __builtin_amdgcn_readlane(idxv[j], jj + 3);
                int s4 = __builtin_amdgcn_readlane(idxv[j], jj + 4);
                int s5 = __builtin_amdgcn_readlane(idxv[j], jj + 5);
                int s6 = __builtin_amdgcn_readlane(idxv[j], jj + 6);
                int s7 = __builtin_amdgcn_readlane(idxv[j], jj + 7);
                float v0 = h[(size_t)s0 * DIM + lane];
                float v1 = h[(size_t)s1 * DIM + lane];
                float v2 = h[(size_t)s2 * DIM + lane];
                float v3 = h[(size_t)s3 * DIM + lane];
                float v4 = h[(size_t)s4 * DIM + lane];
                float v5 = h[(size_t)s5 * DIM + lane];
                float v6 = h[(size_t)s6 * DIM + lane];
                float v7 = h[(size_t)s7 * DIM + lane];
                accv[j] += ((v0 + v1) + (v2 + v3)) + ((v4 + v5) + (v6 + v7));
            }
            if (jj < mr) {   // remaining 4
                int s0 = __builtin_amdgcn_readlane(idxv[j], jj + 0);
                int s1 = __builtin_amdgcn_readlane(idxv[j], jj + 1);
                int s2 = __builtin_amdgcn_readlane(idxv[j], jj + 2);
                int s3 = __builtin_amdgcn_readlane(idxv[j], jj + 3);
                float v0 = h[(size_t)s0 * DIM + lane];
                float v1 = h[(size_t)s1 * DIM + lane];
                float v2 = h[(size_t)s2 * DIM + lane];
                float v3 = h[(size_t)s3 * DIM + lane];
                accv[j] += (v0 + v1) + (v2 + v3);
            }
            H[j * HSTRIDE + lane] = accv[j];
        }
    } else {
        // ---- fallback (deg > 64 somewhere): R6-proven loop ----
        for (int j = 0; j < 16; ++j) {
            const int n = n0 + j;
            const int e0 = __builtin_amdgcn_readlane(rpv, j);
            const int e1 = __builtin_amdgcn_readlane(rpv, j + 1);
            float self = h[(size_t)n * DIM + lane];
            float acc = self;
            for (int base = e0; base < e1; base += 64) {
                const int m  = min(64, e1 - base);
                const int mr = (m + 3) & ~3;
                int idx = (lane < m) ? csr_src[base + lane] : n;
                acc -= (float)(mr - m) * self;
                for (int jj = 0; jj < mr; jj += 4) {
                    int s0 = __builtin_amdgcn_readlane(idx, jj + 0);
                    int s1 = __builtin_amdgcn_readlane(idx, jj + 1);
                    int s2 = __builtin_amdgcn_readlane(idx, jj + 2);
                    int s3 = __builtin_amdgcn_readlane(idx, jj + 3);
                    float v0 = h[(size_t)s0 * DIM + lane];
                    float v1 = h[(size_t)s1 * DIM + lane];
                    float v2 = h[(size_t)s2 * DIM + lane];
                    float v3 = h[(size_t)s3 * DIM + lane];
                    acc += (v0 + v1) + (v2 + v3);
                }
            }
            H[j * HSTRIDE + lane] = acc;
        }
    }
    __syncthreads();

    // ---- MLP: split-bf16 MFMA on rows 0..15 ----
    const int mrow = lane & 15;
    const int quad = lane >> 4;
    const short8* Bf = (const short8*)wf;

    for (int p = 0; p < 3; ++p) {
        short8 Ahi[2], Alo[2];
        #pragma unroll
        for (int kt = 0; kt < 2; ++kt) {
            const float* ap = &H[mrow * HSTRIDE + kt * 32 + quad * 8];
            float4 f0 = *(const float4*)ap;
            float4 f1 = *(const float4*)(ap + 4);
            float fv[8] = {f0.x, f0.y, f0.z, f0.w, f1.x, f1.y, f1.z, f1.w};
            short8 hi, lo;
            #pragma unroll
            for (int jj = 0; jj < 8; ++jj) {
                unsigned short hb = bf16_rne(fv[jj]);
                hi[jj] = (short)hb;
                lo[jj] = (short)bf16_rne(fv[jj] - bf16_f(hb));
            }
            Ahi[kt] = hi; Alo[kt] = lo;
        }

        floatx4 acc[4];
        #pragma unroll
        for (int nt = 0; nt < 4; ++nt) { acc[nt][0]=0.f; acc[nt][1]=0.f; acc[nt][2]=0.f; acc[nt][3]=0.f; }

        #pragma unroll
        for (int nt = 0; nt < 4; ++nt) {
            #pragma unroll
            for (int kt = 0; kt < 2; ++kt) {
                int fbase = (((p * 2 + kt) * 4 + nt) * 2) * 64 + lane;
                short8 bhi = Bf[fbase];
                short8 blo = Bf[fbase + 64];
                acc[nt] = __builtin_amdgcn_mfma_f32_16x16x32_bf16(Alo[kt], bhi, acc[nt], 0, 0, 0);
                acc[nt] = __builtin_amdgcn_mfma_f32_16x16x32_bf16(Ahi[kt], blo, acc[nt], 0, 0, 0);
                acc[nt] = __builtin_amdgcn_mfma_f32_16x16x32_bf16(Ahi[kt], bhi, acc[nt], 0, 0, 0);
            }
        }
        __syncthreads();
        #pragma unroll
        for (int nt = 0; nt < 4; ++nt) {
            #pragma unroll
            for (int reg = 0; reg < 4; ++reg) {
                int row = quad * 4 + reg;
                H[row * HSTRIDE + nt * 16 + mrow] = fmaxf(acc[nt][reg], 0.f);
            }
        }
        __syncthreads();
    }

    // ---- store h for next layer (coalesced, exact fit) ----
    #pragma unroll
    for (int i = 0; i < 4; ++i) {
        int f4 = lane + i * BLK;
        int r  = f4 >> 4;
        int c  = (f4 & 15) << 2;
        *(float4*)(h_out + (size_t)(n0 + r) * DIM + c) = *(const float4*)&H[r * HSTRIDE + c];
    }

    // ---- pool partial into replicated slot (cuts same-address atomic serialization) ----
    {
        float s = 0.f;
        #pragma unroll
        for (int r = 0; r < ROWS; ++r)
            s += H[r * HSTRIDE + lane];
        atomicAdd(&pooled[(blockIdx.x & (POOL_REP - 1)) * DIM + lane], s);
    }
}

__global__ void finalize_kernel(const float* __restrict__ pooled,  // [L][POOL_REP][64]
                                const float* __restrict__ Wl,
                                float* __restrict__ out) {
    int c = threadIdx.x;  // 64
    float s = 0.f;
    #pragma unroll
    for (int l = 0; l < N_LAYERS; ++l) {
        float col = 0.f;
        #pragma unroll
        for (int r = 0; r < POOL_REP; ++r)
            col += pooled[(l * POOL_REP + r) * DIM + c];
        s += col * Wl[l * DIM + c];
    }
    #pragma unroll
    for (int off = 32; off > 0; off >>= 1)
        s += __shfl_down(s, off, 64);
    if (c == 0) {
        float logit = s / (float)N_NODES;
        out[0] = 1.f / (1.f + expf(-logit));
    }
}

extern "C" void kernel_launch(void* const* d_in, const int* in_sizes, int n_in,
                              void* d_out, int out_size, void* d_ws, size_t ws_size,
                              hipStream_t stream) {
    const float* x   = (const float*)d_in[0];
    const float* W   = (const float*)d_in[1];
    const float* Wl  = (const float*)d_in[2];
    const int*   src = (const int*)d_in[3];
    const int*   dst = (const int*)d_in[4];
    float* out = (float*)d_out;

    char* ws = (char*)d_ws;
    const size_t nodeBytes = (size_t)N_NODES * DIM * sizeof(float);   // 12.8 MB
    float* hA       = (float*)(ws);
    float* hB       = (float*)(ws + nodeBytes);
    int*   csr_src  = (int*)  (ws + 2 * nodeBytes);                   // 3.2 MB
    int*   rowptr   = (int*)  (ws + 2 * nodeBytes + (size_t)N_EDGES * 4);
    int*   counts   = rowptr + (N_NODES + 1);
    int*   cursor   = counts + N_NODES;
    int*   blockSums= cursor + N_NODES;
    int*   blockOffs= blockSums + SCAN_BLOCKS;
    float* pooled   = (float*)(blockOffs + SCAN_BLOCKS);              // 5*16*64 floats
    unsigned short* wfrag = (unsigned short*)(pooled + N_LAYERS * POOL_REP * DIM);

    hipMemsetAsync(counts, 0, N_NODES * sizeof(int), stream);
    hipMemsetAsync(cursor, 0, N_NODES * sizeof(int), stream);
    hipMemsetAsync(pooled, 0, N_LAYERS * POOL_REP * DIM * sizeof(float), stream);

    wprep_kernel<<<(N_LAYERS * WFRAG_PER_LAYER + 255) / 256, 256, 0, stream>>>(W, wfrag);
    hist_kernel<<<(N_EDGES + 255) / 256, 256, 0, stream>>>(dst, counts);
    scan_a<<<SCAN_BLOCKS, 256, 0, stream>>>(counts, rowptr, blockSums);
    scan_b<<<1, 256, 0, stream>>>(blockSums, blockOffs);
    scan_c<<<SCAN_BLOCKS, 256, 0, stream>>>(rowptr, blockOffs);
    fill_kernel<<<(N_EDGES + 255) / 256, 256, 0, stream>>>(src, dst, rowptr, cursor, csr_src);

    const float* hcur = x;
    float* hnext = hA;
    for (int l = 0; l < N_LAYERS; ++l) {
        layer_kernel<<<N_NODES / ROWS, BLK, 0, stream>>>(
            hcur, rowptr, csr_src, wfrag + (size_t)l * WFRAG_PER_LAYER, hnext,
            pooled + (size_t)l * POOL_REP * DIM);
        hcur = hnext;
        hnext = (hnext == hA) ? hB : hA;
    }
    finalize_kernel<<<1, 64, 0, stream>>>(pooled, Wl, out);
}

// Round 9
// 341.465 us; speedup vs baseline: 1.5552x; 1.0119x over previous
//
#include <hip/hip_runtime.h>
#include <math.h>

#define N_NODES 50000
#define N_EDGES 800000
#define DIM 64
#define N_LAYERS 5

#define BLK 128      // two waves per block
#define ROWS 32      // 16 rows per wave
#define HSTRIDE 68   // 16B-aligned rows for ds_read_b128; bank=(4r+lane)%32 conflict-free
#define POOL_REP 16

#define SCAN_BLOCKS ((N_NODES + 255) / 256)   // 196 (covers N_NODES+64 pad too)
#define WFRAG_PER_LAYER (3 * 2 * 4 * 2 * 64 * 8)   // 24576 shorts = 49152 B

typedef __attribute__((ext_vector_type(8))) short short8;
typedef __attribute__((ext_vector_type(4))) float floatx4;

__device__ inline unsigned short bf16_rne(float f) {
    unsigned int u = __float_as_uint(f);
    return (unsigned short)((u + 0x7FFFu + ((u >> 16) & 1u)) >> 16);
}
__device__ inline float bf16_f(unsigned short h) {
    return __uint_as_float(((unsigned int)h) << 16);
}

// ---------------- CSR build ----------------

__global__ __launch_bounds__(256) void hist_kernel(const int* __restrict__ dst,
                                                   int* __restrict__ counts) {
    int e = blockIdx.x * 256 + threadIdx.x;
    if (e < N_EDGES) atomicAdd(&counts[dst[e]], 1);
}

__global__ __launch_bounds__(256) void scan_a(const int* __restrict__ counts,
                                              int* __restrict__ rowptr,
                                              int* __restrict__ blockSums) {
    __shared__ int s[256];
    int t = threadIdx.x;
    int g = blockIdx.x * 256 + t;
    int v = (g < N_NODES) ? counts[g] : 0;
    s[t] = v;
    __syncthreads();
    #pragma unroll
    for (int off = 1; off < 256; off <<= 1) {
        int u = (t >= off) ? s[t - off] : 0;
        __syncthreads();
        s[t] += u;
        __syncthreads();
    }
    if (g < N_NODES) rowptr[g] = s[t] - v;
    if (t == 255) blockSums[blockIdx.x] = s[255];
}

__global__ __launch_bounds__(256) void scan_b(const int* __restrict__ blockSums,
                                              int* __restrict__ blockOffs) {
    __shared__ int s[256];
    int t = threadIdx.x;
    int v = (t < SCAN_BLOCKS) ? blockSums[t] : 0;
    s[t] = v;
    __syncthreads();
    #pragma unroll
    for (int off = 1; off < 256; off <<= 1) {
        int u = (t >= off) ? s[t - off] : 0;
        __syncthreads();
        s[t] += u;
        __syncthreads();
    }
    if (t < SCAN_BLOCKS) blockOffs[t] = s[t] - v;
}

__global__ __launch_bounds__(256) void scan_c(int* __restrict__ rowptr,
                                              const int* __restrict__ blockOffs) {
    int t = threadIdx.x;
    int g = blockIdx.x * 256 + t;
    if (g < N_NODES) rowptr[g] += blockOffs[blockIdx.x];
    else if (g <= N_NODES + 63) rowptr[g] = N_EDGES;   // pad tail for 32-row blocks
}

__global__ __launch_bounds__(256) void fill_kernel(const int* __restrict__ src,
                                                   const int* __restrict__ dst,
                                                   const int* __restrict__ rowptr,
                                                   int* __restrict__ cursor,
                                                   int* __restrict__ csr_src) {
    int e = blockIdx.x * 256 + threadIdx.x;
    if (e >= N_EDGES) return;
    int d = dst[e];
    int pos = atomicAdd(&cursor[d], 1);
    csr_src[rowptr[d] + pos] = src[e];
}

// ---------------- input x -> bf16 ----------------
__global__ __launch_bounds__(256) void xprep_kernel(const float* __restrict__ x,
                                                    unsigned short* __restrict__ x16) {
    int i = blockIdx.x * 256 + threadIdx.x;   // one float4 per thread
    if (i >= N_NODES * DIM / 4) return;
    float4 v = ((const float4*)x)[i];
    ushort4 u;
    u.x = bf16_rne(v.x); u.y = bf16_rne(v.y);
    u.z = bf16_rne(v.z); u.w = bf16_rne(v.w);
    ((ushort4*)x16)[i] = u;
}

// ---------------- W -> split-bf16 MFMA B-fragments ----------------
__global__ __launch_bounds__(256) void wprep_kernel(const float* __restrict__ W,
                                                    unsigned short* __restrict__ wfrag) {
    int t = blockIdx.x * 256 + threadIdx.x;
    if (t >= N_LAYERS * WFRAG_PER_LAYER) return;
    int j    = t & 7;
    int lane = (t >> 3) & 63;
    int hl   = (t >> 9) & 1;
    int nt   = (t >> 10) & 3;
    int kt   = (t >> 12) & 1;
    int rest = t >> 13;
    int p    = rest % 3;
    int layer= rest / 3;
    int k = kt * 32 + (lane >> 4) * 8 + j;
    int n = nt * 16 + (lane & 15);
    float v = W[(((size_t)layer * 3 + p) * 64 + k) * 64 + n];
    unsigned short hi = bf16_rne(v);
    wfrag[t] = hl ? bf16_rne(v - bf16_f(hi)) : hi;
}

// ---------------- fused layer: 2 waves x 16 nodes, bf16 h storage ----------------
__global__ __launch_bounds__(BLK) void layer_kernel(const unsigned short* __restrict__ h16,
                                                    const int* __restrict__ rowptr,
                                                    const int* __restrict__ csr_src,
                                                    const unsigned short* __restrict__ wf,
                                                    unsigned short* __restrict__ h_out,
                                                    float* __restrict__ pooled) {  // [POOL_REP][64]
    __shared__ float H[ROWS * HSTRIDE];   // 8.7 KB
    const int tid  = threadIdx.x;
    const int lane = tid & 63;
    const int w    = __builtin_amdgcn_readfirstlane(tid >> 6);   // wave 0/1
    const int n0   = blockIdx.x * ROWS;
    const int nw   = n0 + w * 16;          // this wave's first node

    // rowptr[nw .. nw+16] in one coalesced load (rowptr padded past N_NODES)
    int rpv = rowptr[nw + min(lane, 16)];
    int rp_next = __shfl_down(rpv, 1, 64);
    int degl = rp_next - rpv;
    bool big = __ballot(lane < 16 && degl > 64) != 0ull;   // wave-uniform

    if (!big) {
        // ---- fast path: all degrees <= 64 ----
        int e0s[16], degs[16];
        #pragma unroll
        for (int j = 0; j < 16; ++j) {
            e0s[j]  = __builtin_amdgcn_readlane(rpv, j);
            degs[j] = __builtin_amdgcn_readlane(rpv, j + 1) - e0s[j];
        }
        int idxv[16];
        #pragma unroll
        for (int j = 0; j < 16; ++j)
            idxv[j] = (lane < degs[j]) ? csr_src[e0s[j] + lane] : (nw + j);
        float accv[16];
        #pragma unroll
        for (int j = 0; j < 16; ++j)
            accv[j] = (nw + j < N_NODES) ? bf16_f(h16[(size_t)(nw + j) * DIM + lane]) : 0.f;

        #pragma unroll
        for (int j = 0; j < 16; ++j) {
            const int deg = degs[j];
            const int mr  = (deg + 3) & ~3;
            accv[j] *= (float)(1 - (mr - deg));   // pre-cancel padded self-adds
            int jj = 0;
            for (; jj + 8 <= mr; jj += 8) {
                int s0 = __builtin_amdgcn_readlane(idxv[j], jj + 0);
                int s1 = __builtin_amdgcn_readlane(idxv[j], jj + 1);
                int s2 = __builtin_amdgcn_readlane(idxv[j], jj + 2);
                int s3 = __builtin_amdgcn_readlane(idxv[j], jj + 3);
                int s4 = __builtin_amdgcn_readlane(idxv[j], jj + 4);
                int s5 = __builtin_amdgcn_readlane(idxv[j], jj + 5);
                int s6 = __builtin_amdgcn_readlane(idxv[j], jj + 6);
                int s7 = __builtin_amdgcn_readlane(idxv[j], jj + 7);
                float v0 = bf16_f(h16[(size_t)s0 * DIM + lane]);
                float v1 = bf16_f(h16[(size_t)s1 * DIM + lane]);
                float v2 = bf16_f(h16[(size_t)s2 * DIM + lane]);
                float v3 = bf16_f(h16[(size_t)s3 * DIM + lane]);
                float v4 = bf16_f(h16[(size_t)s4 * DIM + lane]);
                float v5 = bf16_f(h16[(size_t)s5 * DIM + lane]);
                float v6 = bf16_f(h16[(size_t)s6 * DIM + lane]);
                float v7 = bf16_f(h16[(size_t)s7 * DIM + lane]);
                accv[j] += ((v0 + v1) + (v2 + v3)) + ((v4 + v5) + (v6 + v7));
            }
            if (jj < mr) {
                int s0 = __builtin_amdgcn_readlane(idxv[j], jj + 0);
                int s1 = __builtin_amdgcn_readlane(idxv[j], jj + 1);
                int s2 = __builtin_amdgcn_readlane(idxv[j], jj + 2);
                int s3 = __builtin_amdgcn_readlane(idxv[j], jj + 3);
                float v0 = bf16_f(h16[(size_t)s0 * DIM + lane]);
                float v1 = bf16_f(h16[(size_t)s1 * DIM + lane]);
                float v2 = bf16_f(h16[(size_t)s2 * DIM + lane]);
                float v3 = bf16_f(h16[(size_t)s3 * DIM + lane]);
                accv[j] += (v0 + v1) + (v2 + v3);
            }
            H[(w * 16 + j) * HSTRIDE + lane] = accv[j];
        }
    } else {
        // ---- fallback (deg > 64 somewhere) ----
        for (int j = 0; j < 16; ++j) {
            const int n = nw + j;
            const int e0 = __builtin_amdgcn_readlane(rpv, j);
            const int e1 = __builtin_amdgcn_readlane(rpv, j + 1);
            float acc = 0.f;
            if (n < N_NODES) {
                float self = bf16_f(h16[(size_t)n * DIM + lane]);
                acc = self;
                for (int base = e0; base < e1; base += 64) {
                    const int m  = min(64, e1 - base);
                    const int mr = (m + 3) & ~3;
                    int idx = (lane < m) ? csr_src[base + lane] : n;
                    acc -= (float)(mr - m) * self;
                    for (int jj = 0; jj < mr; jj += 4) {
                        int s0 = __builtin_amdgcn_readlane(idx, jj + 0);
                        int s1 = __builtin_amdgcn_readlane(idx, jj + 1);
                        int s2 = __builtin_amdgcn_readlane(idx, jj + 2);
                        int s3 = __builtin_amdgcn_readlane(idx, jj + 3);
                        float v0 = bf16_f(h16[(size_t)s0 * DIM + lane]);
                        float v1 = bf16_f(h16[(size_t)s1 * DIM + lane]);
                        float v2 = bf16_f(h16[(size_t)s2 * DIM + lane]);
                        float v3 = bf16_f(h16[(size_t)s3 * DIM + lane]);
                        acc += (v0 + v1) + (v2 + v3);
                    }
                }
            }
            H[(w * 16 + j) * HSTRIDE + lane] = acc;
        }
    }
    __syncthreads();

    // ---- MLP: split-bf16 MFMA; wave w owns rows w*16 .. w*16+15 ----
    const int mrow = lane & 15;
    const int quad = lane >> 4;
    const short8* Bf = (const short8*)wf;

    for (int p = 0; p < 3; ++p) {
        short8 Ahi[2], Alo[2];
        #pragma unroll
        for (int kt = 0; kt < 2; ++kt) {
            const float* ap = &H[(w * 16 + mrow) * HSTRIDE + kt * 32 + quad * 8];
            float4 f0 = *(const float4*)ap;
            float4 f1 = *(const float4*)(ap + 4);
            float fv[8] = {f0.x, f0.y, f0.z, f0.w, f1.x, f1.y, f1.z, f1.w};
            short8 hi, lo;
            #pragma unroll
            for (int jj = 0; jj < 8; ++jj) {
                unsigned short hb = bf16_rne(fv[jj]);
                hi[jj] = (short)hb;
                lo[jj] = (short)bf16_rne(fv[jj] - bf16_f(hb));
            }
            Ahi[kt] = hi; Alo[kt] = lo;
        }

        floatx4 acc[4];
        #pragma unroll
        for (int nt = 0; nt < 4; ++nt) { acc[nt][0]=0.f; acc[nt][1]=0.f; acc[nt][2]=0.f; acc[nt][3]=0.f; }

        #pragma unroll
        for (int nt = 0; nt < 4; ++nt) {
            #pragma unroll
            for (int kt = 0; kt < 2; ++kt) {
                int fbase = (((p * 2 + kt) * 4 + nt) * 2) * 64 + lane;
                short8 bhi = Bf[fbase];
                short8 blo = Bf[fbase + 64];
                acc[nt] = __builtin_amdgcn_mfma_f32_16x16x32_bf16(Alo[kt], bhi, acc[nt], 0, 0, 0);
                acc[nt] = __builtin_amdgcn_mfma_f32_16x16x32_bf16(Ahi[kt], blo, acc[nt], 0, 0, 0);
                acc[nt] = __builtin_amdgcn_mfma_f32_16x16x32_bf16(Ahi[kt], bhi, acc[nt], 0, 0, 0);
            }
        }
        __syncthreads();
        #pragma unroll
        for (int nt = 0; nt < 4; ++nt) {
            #pragma unroll
            for (int reg = 0; reg < 4; ++reg) {
                int row = w * 16 + quad * 4 + reg;
                H[row * HSTRIDE + nt * 16 + mrow] = fmaxf(acc[nt][reg], 0.f);
            }
        }
        __syncthreads();
    }

    // ---- store h as bf16 for next layer (coalesced, guarded tail) ----
    #pragma unroll
    for (int i = 0; i < 4; ++i) {
        int t4 = tid + i * BLK;        // 0..511
        int r  = t4 >> 4;
        int c  = (t4 & 15) << 2;
        int grow = n0 + r;
        if (grow < N_NODES) {
            float4 v = *(const float4*)&H[r * HSTRIDE + c];
            ushort4 u;
            u.x = bf16_rne(v.x); u.y = bf16_rne(v.y);
            u.z = bf16_rne(v.z); u.w = bf16_rne(v.w);
            *(ushort4*)(h_out + (size_t)grow * DIM + c) = u;
        }
    }

    // ---- pool partial (invalid rows hold exact zeros) ----
    if (tid < 64) {
        float s = 0.f;
        #pragma unroll
        for (int r = 0; r < ROWS; ++r)
            s += H[r * HSTRIDE + tid];
        atomicAdd(&pooled[(blockIdx.x & (POOL_REP - 1)) * DIM + tid], s);
    }
}

__global__ void finalize_kernel(const float* __restrict__ pooled,  // [L][POOL_REP][64]
                                const float* __restrict__ Wl,
                                float* __restrict__ out) {
    int c = threadIdx.x;  // 64
    float s = 0.f;
    #pragma unroll
    for (int l = 0; l < N_LAYERS; ++l) {
        float col = 0.f;
        #pragma unroll
        for (int r = 0; r < POOL_REP; ++r)
            col += pooled[(l * POOL_REP + r) * DIM + c];
        s += col * Wl[l * DIM + c];
    }
    #pragma unroll
    for (int off = 32; off > 0; off >>= 1)
        s += __shfl_down(s, off, 64);
    if (c == 0) {
        float logit = s / (float)N_NODES;
        out[0] = 1.f / (1.f + expf(-logit));
    }
}

extern "C" void kernel_launch(void* const* d_in, const int* in_sizes, int n_in,
                              void* d_out, int out_size, void* d_ws, size_t ws_size,
                              hipStream_t stream) {
    const float* x   = (const float*)d_in[0];
    const float* W   = (const float*)d_in[1];
    const float* Wl  = (const float*)d_in[2];
    const int*   src = (const int*)d_in[3];
    const int*   dst = (const int*)d_in[4];
    float* out = (float*)d_out;

    char* ws = (char*)d_ws;
    const size_t h16Bytes = (size_t)N_NODES * DIM * 2;                // 6.4 MB
    unsigned short* hX = (unsigned short*)(ws);                       // x in bf16
    unsigned short* hA = (unsigned short*)(ws + h16Bytes);
    unsigned short* hB = (unsigned short*)(ws + 2 * h16Bytes);
    int*   csr_src  = (int*)  (ws + 3 * h16Bytes);                    // 3.2 MB
    int*   rowptr   = csr_src + N_EDGES;                              // N_NODES+64
    int*   counts   = rowptr + (N_NODES + 64);
    int*   cursor   = counts + N_NODES;
    int*   blockSums= cursor + N_NODES;
    int*   blockOffs= blockSums + SCAN_BLOCKS;
    float* pooled   = (float*)(blockOffs + SCAN_BLOCKS);              // 5*16*64 floats
    unsigned short* wfrag = (unsigned short*)(pooled + N_LAYERS * POOL_REP * DIM);

    hipMemsetAsync(counts, 0, N_NODES * sizeof(int), stream);
    hipMemsetAsync(cursor, 0, N_NODES * sizeof(int), stream);
    hipMemsetAsync(pooled, 0, N_LAYERS * POOL_REP * DIM * sizeof(float), stream);

    xprep_kernel<<<(N_NODES * DIM / 4 + 255) / 256, 256, 0, stream>>>(x, hX);
    wprep_kernel<<<(N_LAYERS * WFRAG_PER_LAYER + 255) / 256, 256, 0, stream>>>(W, wfrag);
    hist_kernel<<<(N_EDGES + 255) / 256, 256, 0, stream>>>(dst, counts);
    scan_a<<<SCAN_BLOCKS, 256, 0, stream>>>(counts, rowptr, blockSums);
    scan_b<<<1, 256, 0, stream>>>(blockSums, blockOffs);
    scan_c<<<SCAN_BLOCKS, 256, 0, stream>>>(rowptr, blockOffs);
    fill_kernel<<<(N_EDGES + 255) / 256, 256, 0, stream>>>(src, dst, rowptr, cursor, csr_src);

    const unsigned short* hcur = hX;
    unsigned short* hnext = hA;
    const int grid = (N_NODES + ROWS - 1) / ROWS;   // 1563
    for (int l = 0; l < N_LAYERS; ++l) {
        layer_kernel<<<grid, BLK, 0, stream>>>(
            hcur, rowptr, csr_src, wfrag + (size_t)l * WFRAG_PER_LAYER, hnext,
            pooled + (size_t)l * POOL_REP * DIM);
        hcur = hnext;
        hnext = (hnext == hA) ? hB : hA;
    }
    finalize_kernel<<<1, 64, 0, stream>>>(pooled, Wl, out);
}